// Round 13
// baseline (170.702 us; speedup 1.0000x reference)
//
#include <hip/hip_runtime.h>
#include <hip/hip_bf16.h>

#define Bn  2
#define Nn  768
#define Dh  32
#define DMm 64
#define KK  16
#define GI  3                // i's per main block -> grid 512
#define TPRE 256
#define TMAIN 256            // 4 waves/block: lifts VGPR cap 128 -> 256 (r11/r12 spilled at 128)

typedef __bf16 bf16x8 __attribute__((ext_vector_type(8)));
typedef float  f32x4  __attribute__((ext_vector_type(4)));

// ws layout (bytes):
//   G1     bf16[98304]  @ 0        (196608)
//   G2     f32 [98304]  @ 196608   (393216)
//   W1f    bf16[4096]   @ 589824   (8192)   e1W folded; A-frag of W1^T == B-frag of W1
//   W2Tf   bf16[4096]   @ 598016   (8192)   c0W^T folded, k-permuted by pi
//   o1v    f32[64]      @ 606208
//   o2w3   f32[2048]    @ 606464   (8192)
//   Wnf    f32[3072]    @ 614656   (12288)
//   onOff  f32[32]      @ 626944
//   wd2    f32[64]      @ 627072
//   misc   f32[4]       @ 627328
//   knnIdx int[24576]   @ 627456   (98304)
//   o1p    f32[1024]    @ 725760   (4096)

// ---------------- phase 1: knn (blocks 0..383), G1/G2 (384..431), packing (432)
__global__ __launch_bounds__(TPRE) void egnn_pre(
    const float* __restrict__ X,  const float* __restrict__ H,
    const float* __restrict__ e0W, const float* __restrict__ e0b,
    const float* __restrict__ e0s, const float* __restrict__ e0t,
    const float* __restrict__ e1W, const float* __restrict__ e1b,
    const float* __restrict__ e1s, const float* __restrict__ e1t,
    const float* __restrict__ c0W, const float* __restrict__ c0b,
    const float* __restrict__ c0s, const float* __restrict__ c0t,
    const float* __restrict__ c1W, const float* __restrict__ c1b,
    const float* __restrict__ c1s, const float* __restrict__ c1t,
    const float* __restrict__ n0W, const float* __restrict__ n0b,
    const float* __restrict__ n0s, const float* __restrict__ n0t,
    __bf16* __restrict__ G1, float* __restrict__ G2,
    __bf16* __restrict__ W1f, __bf16* __restrict__ W2Tf,
    float* __restrict__ o1v, float* __restrict__ o2w3,
    float* __restrict__ Wnf, float* __restrict__ onOff,
    float* __restrict__ wd2, float* __restrict__ misc,
    int* __restrict__ knnIdx, float* __restrict__ o1p)
{
    const int tid = threadIdx.x;
    if (blockIdx.x < 384) {
        // ---- knn: one wave per i ----
        const int lane = tid & 63;
        const int row_i = blockIdx.x * 4 + (tid >> 6);   // 0..1535
        const int b = row_i / Nn;
        const float xi0 = X[(size_t)row_i * 3 + 0];
        const float xi1 = X[(size_t)row_i * 3 + 1];
        const float xi2 = X[(size_t)row_i * 3 + 2];
        float v[Nn / 64];
        #pragma unroll
        for (int k = 0; k < Nn / 64; ++k) {
            int j = lane + (k << 6);
            size_t rj = (size_t)(b * Nn + j) * 3;
            float dx = X[rj + 0] - xi0;
            float dy = X[rj + 1] - xi1;
            float dz = X[rj + 2] - xi2;
            v[k] = __fadd_rn(__fadd_rn(__fmul_rn(dx, dx), __fmul_rn(dy, dy)),
                             __fmul_rn(dz, dz));
        }
        for (int r = 0; r < KK; ++r) {
            float bv = 3.4e38f; int bidx = Nn;
            #pragma unroll
            for (int k = 0; k < Nn / 64; ++k)
                if (v[k] < bv) { bv = v[k]; bidx = lane + (k << 6); }
            #pragma unroll
            for (int off = 32; off >= 1; off >>= 1) {
                float ov = __shfl_down(bv, off);
                int   oi = __shfl_down(bidx, off);
                if (ov < bv || (ov == bv && oi < bidx)) { bv = ov; bidx = oi; }
            }
            bidx = __shfl(bidx, 0);
            if (lane == 0) knnIdx[row_i * KK + r] = bidx;
            if ((bidx & 63) == lane) v[bidx >> 6] = 3.4e38f;
        }
    } else if (blockIdx.x < 432) {
        // ---- G1/G2: 48 blocks x 32 rows ----
        __shared__ float sWa[Dh * DMm], sWb[Dh * DMm], sOff[DMm], sH[32 * Dh];
        for (int k = tid; k < Dh * DMm; k += TPRE) {
            float s = e0s[k & 63];
            sWa[k] = e0W[k] * s;
            sWb[k] = e0W[Dh * DMm + k] * s;
        }
        if (tid < DMm) sOff[tid] = fmaf(e0b[tid], e0s[tid], e0t[tid]);
        const int row0 = (blockIdx.x - 384) * 32;
        for (int k = tid; k < 32 * Dh; k += TPRE) sH[k] = H[(size_t)row0 * Dh + k];
        __syncthreads();

        const int r = tid >> 3, g = tid & 7;
        float g1[8], g2[8];
        #pragma unroll
        for (int e = 0; e < 8; ++e) { g1[e] = 0.f; g2[e] = sOff[g * 8 + e]; }
        #pragma unroll
        for (int d = 0; d < Dh; ++d) {
            float hv = sH[r * Dh + d];
            #pragma unroll
            for (int e = 0; e < 8; ++e) {
                g1[e] = fmaf(hv, sWa[d * DMm + g * 8 + e], g1[e]);
                g2[e] = fmaf(hv, sWb[d * DMm + g * 8 + e], g2[e]);
            }
        }
        const size_t row = row0 + r;
        bf16x8 o;
        #pragma unroll
        for (int e = 0; e < 8; ++e) o[e] = (__bf16)g1[e];
        *(bf16x8*)(G1 + row * DMm + g * 8) = o;
        *(float4*)(G2 + row * DMm + g * 8)     = make_float4(g2[0], g2[1], g2[2], g2[3]);
        *(float4*)(G2 + row * DMm + g * 8 + 4) = make_float4(g2[4], g2[5], g2[6], g2[7]);
    } else {
        // ---- weight packing ----
        for (int src = tid; src < 4096; src += TPRE) {
            int k = src >> 6, n = src & 63;
            int fi1 = ((((k >> 5) * 4 + (n >> 4)) * 64) + ((k >> 3) & 3) * 16 + (n & 15)) * 8 + (k & 7);
            W1f[fi1] = (__bf16)(e1W[src] * e1s[n]);
            // W2Tf with pi-permuted k: ch1 = (2s+u)*16 + q*4 + r, ch2 = t4*16 + l15
            int ch1 = k, ch2 = n;
            int s2 = ch1 >> 5, u2 = (ch1 >> 4) & 1, q2 = (ch1 >> 2) & 3, r2 = ch1 & 3;
            int fi2 = (((s2 * 4 + (ch2 >> 4)) * 64) + q2 * 16 + (ch2 & 15)) * 8 + (u2 * 4 + r2);
            W2Tf[fi2] = (__bf16)(c0W[src] * c0s[ch2]);
        }
        if (tid < DMm) {
            o1v[tid] = fmaf(e1b[tid], e1s[tid], e1t[tid]);
            wd2[tid] = e0W[64 * DMm + tid] * e0s[tid];
        }
        for (int u = tid; u < 1024; u += TPRE) {
            int lane = u >> 4, t4 = (u >> 2) & 3, r = u & 3;
            int ch = t4 * 16 + ((lane >> 4) & 3) * 4 + r;
            o1p[u] = fmaf(e1b[ch], e1s[ch], e1t[ch]);
        }
        for (int u = tid; u < 1024; u += TPRE) {
            int lane = u >> 4, rem = u & 15, t4 = rem >> 2, r = rem & 3;
            int ch = t4 * 16 + (lane >> 4) * 4 + r;
            o2w3[2 * u]     = fmaf(c0b[ch], c0s[ch], c0t[ch]);
            o2w3[2 * u + 1] = c1W[ch] * c1s[0];
        }
        for (int idx = tid; idx < (Dh + DMm) * Dh; idx += TPRE)
            Wnf[idx] = n0W[idx] * n0s[idx & 31];
        if (tid < Dh) onOff[tid] = fmaf(n0b[tid], n0s[tid], n0t[tid]);
        if (tid == 0) misc[0] = fmaf(c1b[0], c1s[0], c1t[0]);
    }
}

// ---------------- phase 2: GI=3 i's per block, 4 waves of 256, grid 512
// r11/r12 lesson: at 512 threads __launch_bounds__(512,2) caps VGPR at 128 and
// every ILP/prefetch variant spills. 256-thread blocks lift the cap to 256+,
// letting the r12 1-deep prefetch live in registers. r8/r9 showed resident-wave
// count is NOT the limiter (chain-bound), so halving waves/CU costs ~nothing.
__global__ __launch_bounds__(TMAIN) void egnn_main(
    const float* __restrict__ X,  const float* __restrict__ H,
    const __bf16* __restrict__ G1, const float* __restrict__ G2,
    const __bf16* __restrict__ W1f, const __bf16* __restrict__ W2Tf,
    const float* __restrict__ o1p, const float* __restrict__ o2w3,
    const float* __restrict__ Wnf, const float* __restrict__ onOff,
    const float* __restrict__ wd2, const float* __restrict__ misc,
    const int* __restrict__ knnIdx,
    float* __restrict__ out)
{
    const int bid = blockIdx.x;               // 0..511
    const int b  = bid >> 8;
    const int i0 = (bid & 255) * GI;
    const int tid = threadIdx.x;
    const int wv = tid >> 6;                  // 0..3
    const int lane = tid & 63;
    const int l15 = lane & 15;
    const int q   = lane >> 4;

    __shared__ float  sX[Nn * 3];             // 9216
    __shared__ float  sD2[GI * Nn];           // 9216  (sign bit = knn-hit flag)
    __shared__ float  sWj[GI * Nn];           // 9216
    __shared__ float  sMnode[GI * DMm];       // 768
    __shared__ float  sFeat[GI * 96];         // 1152
    __shared__ float  sXacc[GI * 3];
    // total ~29.6 KB

    // ---- phase A1: staging + clears ----
    for (int k = tid; k < Nn * 3; k += TMAIN) sX[k] = X[(size_t)b * Nn * 3 + k];
    if (tid < GI * DMm) sMnode[tid] = 0.f;
    if (tid < GI * Dh) {
        int i_l = tid >> 5, c = tid & 31;
        sFeat[i_l * 96 + c] = H[(size_t)(b * Nn + i0 + i_l) * Dh + c];
    }
    __syncthreads();

    // ---- phase A2: d2 for GI i's ----
    #pragma unroll
    for (int i_l = 0; i_l < GI; ++i_l) {
        float xi0 = sX[(i0 + i_l) * 3 + 0];
        float xi1 = sX[(i0 + i_l) * 3 + 1];
        float xi2 = sX[(i0 + i_l) * 3 + 2];
        for (int j = tid; j < Nn; j += TMAIN) {
            float dx = sX[j * 3 + 0] - xi0;
            float dy = sX[j * 3 + 1] - xi1;
            float dz = sX[j * 3 + 2] - xi2;
            sD2[i_l * Nn + j] = __fadd_rn(__fadd_rn(__fmul_rn(dx, dx), __fmul_rn(dy, dy)),
                                          __fmul_rn(dz, dz));
        }
    }
    __syncthreads();
    // knn hit flags: sign bit of sD2 at knn indices (distinct -> race-free)
    if (tid < GI * KK) {
        int i_l = tid >> 4, r = tid & 15;
        int idx = knnIdx[(size_t)(b * Nn + i0 + i_l) * KK + r];
        ((unsigned*)sD2)[i_l * Nn + idx] |= 0x80000000u;
    }

    // ---- hoist weight fragments + per-lane constants (registers) ----
    bf16x8 w1f[2][4], w2f[2][4];
    #pragma unroll
    for (int s = 0; s < 2; ++s)
        #pragma unroll
        for (int t4 = 0; t4 < 4; ++t4) {
            w1f[s][t4] = *(const bf16x8*)(W1f + (((s * 4 + t4) * 64 + lane) << 3));
            w2f[s][t4] = *(const bf16x8*)(W2Tf + (((s * 4 + t4) * 64 + lane) << 3));
        }
    bf16x8 wd2b[2];
    #pragma unroll
    for (int s = 0; s < 2; ++s) {
        const float4* wp = (const float4*)(wd2 + s * 32 + q * 8);
        float4 wa = wp[0], wc = wp[1];
        float t[8] = {wa.x, wa.y, wa.z, wa.w, wc.x, wc.y, wc.z, wc.w};
        bf16x8 o;
        #pragma unroll
        for (int e = 0; e < 8; ++e) o[e] = (__bf16)t[e];
        wd2b[s] = o;
    }
    f32x4 o1q[4];
    #pragma unroll
    for (int t4 = 0; t4 < 4; ++t4)
        o1q[t4] = *(const f32x4*)(o1p + lane * 16 + t4 * 4);
    float4 o2w3q[8];
    #pragma unroll
    for (int u = 0; u < 8; ++u) o2w3q[u] = ((const float4*)o2w3)[lane * 8 + u];
    const float c1off = misc[0];
    __syncthreads();

    // ---- main loop: i_l outer; unrolled 12-iteration m-loop, 1-deep prefetch ----
    for (int i_l = 0; i_l < GI; ++i_l) {
        const int ig = i0 + i_l;
        bf16x8 g2b[2];
        #pragma unroll
        for (int s = 0; s < 2; ++s) {
            const float4* gp = (const float4*)(G2 + (size_t)(b * Nn + ig) * DMm + s * 32 + q * 8);
            float4 ga = gp[0], gc = gp[1];
            float t[8] = {ga.x, ga.y, ga.z, ga.w, gc.x, gc.y, gc.z, gc.w};
            bf16x8 o;
            #pragma unroll
            for (int e = 0; e < 8; ++e) o[e] = (__bf16)t[e];
            g2b[s] = o;
        }

        // prologue: load iteration 0's d2 + G1
        unsigned du = __float_as_uint(sD2[i_l * Nn + wv * 16 + l15]);
        bf16x8 g1v[2];
        #pragma unroll
        for (int s = 0; s < 2; ++s)
            g1v[s] = *(const bf16x8*)(G1 + (size_t)(b * Nn + wv * 16 + l15) * DMm + s * 32 + q * 8);

        #pragma unroll
        for (int m = 0; m < 12; ++m) {
            const int base = (wv + 4 * m) * 16;

            // prefetch next iteration's loads (independent of current compute)
            unsigned du_n = 0;
            bf16x8 g1n[2] = {bf16x8{}, bf16x8{}};
            if (m < 11) {
                const int jn = base + 64 + l15;
                du_n = __float_as_uint(sD2[i_l * Nn + jn]);
                #pragma unroll
                for (int s = 0; s < 2; ++s)
                    g1n[s] = *(const bf16x8*)(G1 + (size_t)(b * Nn + jn) * DMm + s * 32 + q * 8);
            }

            // a0 fragments (B operand: B[k=ch0][n=j=l15])
            float d2v = __uint_as_float(du & 0x7fffffffu);
            bool hit = (du >> 31) != 0;
            bf16x8 a0f[2];
            #pragma unroll
            for (int s = 0; s < 2; ++s) {
                bf16x8 af;
                #pragma unroll
                for (int e = 0; e < 8; ++e) {
                    float v = fmaf(d2v, (float)wd2b[s][e], (float)g2b[s][e]) + (float)g1v[s][e];
                    af[e] = (__bf16)fmaxf(v, 0.f);
                }
                a0f[s] = af;
            }

            // e1 transposed: acc1 = W1^T x a0^T + o1
            f32x4 acc1[4];
            #pragma unroll
            for (int t4 = 0; t4 < 4; ++t4) acc1[t4] = o1q[t4];
            #pragma unroll
            for (int s = 0; s < 2; ++s)
                #pragma unroll
                for (int t4 = 0; t4 < 4; ++t4)
                    acc1[t4] = __builtin_amdgcn_mfma_f32_16x16x32_bf16(w1f[s][t4], a0f[s], acc1[t4], 0, 0, 0);
            #pragma unroll
            for (int t4 = 0; t4 < 4; ++t4)
                #pragma unroll
                for (int r = 0; r < 4; ++r)
                    acc1[t4][r] = fmaxf(acc1[t4][r], 0.f);

            // m_node (rare)
            if (hit) {
                #pragma unroll
                for (int t4 = 0; t4 < 4; ++t4)
                    #pragma unroll
                    for (int r = 0; r < 4; ++r)
                        atomicAdd(&sMnode[i_l * DMm + t4 * 16 + q * 4 + r], acc1[t4][r]);
            }

            // in-register transpose via pi
            bf16x8 bfr[2];
            #pragma unroll
            for (int s = 0; s < 2; ++s) {
                bf16x8 o;
                #pragma unroll
                for (int u = 0; u < 2; ++u)
                    #pragma unroll
                    for (int r = 0; r < 4; ++r)
                        o[u * 4 + r] = (__bf16)acc1[2 * s + u][r];
                bfr[s] = o;
            }

            // c0 (pi-permuted k) + 4-partial c1 dot
            f32x4 acc2[4];
            #pragma unroll
            for (int t4 = 0; t4 < 4; ++t4) acc2[t4] = f32x4{0.f, 0.f, 0.f, 0.f};
            #pragma unroll
            for (int s = 0; s < 2; ++s)
                #pragma unroll
                for (int t4 = 0; t4 < 4; ++t4)
                    acc2[t4] = __builtin_amdgcn_mfma_f32_16x16x32_bf16(w2f[s][t4], bfr[s], acc2[t4], 0, 0, 0);
            float pp[4] = {0.f, 0.f, 0.f, 0.f};
            #pragma unroll
            for (int t4 = 0; t4 < 4; ++t4)
                #pragma unroll
                for (int r = 0; r < 4; ++r) {
                    int u = t4 * 4 + r;
                    float4 qv = o2w3q[u >> 1];
                    float o2 = (u & 1) ? qv.z : qv.x;
                    float w3 = (u & 1) ? qv.w : qv.y;
                    pp[t4] = fmaf(fmaxf(acc2[t4][r] + o2, 0.f), w3, pp[t4]);
                }
            float p = (pp[0] + pp[1]) + (pp[2] + pp[3]);
            p += __shfl_xor(p, 16);
            p += __shfl_xor(p, 32);
            if (lane < 16) sWj[i_l * Nn + base + l15] = fmaxf(p + c1off, 0.f);

            // rotate prefetched state in
            du = du_n;
            g1v[0] = g1n[0];
            g1v[1] = g1n[1];
        }
    }
    __syncthreads();

    // ---- epilogue 1: xacc (waves 0..GI-1, one i each) + m_node -> sFeat ----
    if (wv < GI) {
        const int i_l = wv;
        float xi0 = sX[(i0 + i_l) * 3 + 0];
        float xi1 = sX[(i0 + i_l) * 3 + 1];
        float xi2 = sX[(i0 + i_l) * 3 + 2];
        float xa0 = 0.f, xa1 = 0.f, xa2 = 0.f;
        #pragma unroll
        for (int k = 0; k < Nn / 64; ++k) {
            int j = lane + (k << 6);
            float w = sWj[i_l * Nn + j];
            xa0 = fmaf(w, sX[j * 3 + 0] - xi0, xa0);
            xa1 = fmaf(w, sX[j * 3 + 1] - xi1, xa1);
            xa2 = fmaf(w, sX[j * 3 + 2] - xi2, xa2);
        }
        #pragma unroll
        for (int off = 32; off >= 1; off >>= 1) {
            xa0 += __shfl_down(xa0, off);
            xa1 += __shfl_down(xa1, off);
            xa2 += __shfl_down(xa2, off);
        }
        if (lane == 0) {
            sXacc[i_l * 3 + 0] = xa0;
            sXacc[i_l * 3 + 1] = xa1;
            sXacc[i_l * 3 + 2] = xa2;
        }
    }
    if (tid < GI * DMm) {
        int i_l = tid >> 6, ch = tid & 63;
        sFeat[i_l * 96 + Dh + ch] = sMnode[tid];
    }
    __syncthreads();

    // ---- epilogue 2: n0 layer + stores ----
    if (tid < GI * Dh) {
        int i_l = tid >> 5, oc = tid & 31;
        float z = onOff[oc];
        #pragma unroll
        for (int c = 0; c < Dh + DMm; ++c)
            z = fmaf(sFeat[i_l * 96 + c], Wnf[c * Dh + oc], z);
        out[(size_t)Bn * Nn * 3 + (size_t)(b * Nn + i0 + i_l) * Dh + oc] = fmaxf(z, 0.f);
    }
    if (tid < GI * 3) {
        int i_l = tid / 3, c = tid - i_l * 3;
        out[(size_t)(b * Nn + i0 + i_l) * 3 + c] = sX[(i0 + i_l) * 3 + c] + sXacc[i_l * 3 + c];
    }
}

extern "C" void kernel_launch(void* const* d_in, const int* in_sizes, int n_in,
                              void* d_out, int out_size, void* d_ws, size_t ws_size,
                              hipStream_t stream) {
    const float* X   = (const float*)d_in[0];
    const float* H   = (const float*)d_in[1];
    const float* e0W = (const float*)d_in[2];
    const float* e0b = (const float*)d_in[3];
    const float* e0s = (const float*)d_in[4];
    const float* e0t = (const float*)d_in[5];
    const float* e1W = (const float*)d_in[6];
    const float* e1b = (const float*)d_in[7];
    const float* e1s = (const float*)d_in[8];
    const float* e1t = (const float*)d_in[9];
    const float* c0W = (const float*)d_in[10];
    const float* c0b = (const float*)d_in[11];
    const float* c0s = (const float*)d_in[12];
    const float* c0t = (const float*)d_in[13];
    const float* c1W = (const float*)d_in[14];
    const float* c1b = (const float*)d_in[15];
    const float* c1s = (const float*)d_in[16];
    const float* c1t = (const float*)d_in[17];
    const float* n0W = (const float*)d_in[18];
    const float* n0b = (const float*)d_in[19];
    const float* n0s = (const float*)d_in[20];
    const float* n0t = (const float*)d_in[21];
    float* out = (float*)d_out;

    char* ws = (char*)d_ws;
    __bf16* G1    = (__bf16*)(ws);
    float*  G2    = (float*)(ws + 196608);
    __bf16* W1f   = (__bf16*)(ws + 589824);
    __bf16* W2Tf  = (__bf16*)(ws + 598016);
    float*  o1v   = (float*)(ws + 606208);
    float*  o2w3  = (float*)(ws + 606464);
    float*  Wnf   = (float*)(ws + 614656);
    float*  onOff = (float*)(ws + 626944);
    float*  wd2   = (float*)(ws + 627072);
    float*  misc  = (float*)(ws + 627328);
    int*    knnIdx= (int*)(ws + 627456);
    float*  o1p   = (float*)(ws + 725760);

    egnn_pre<<<dim3(433), dim3(TPRE), 0, stream>>>(X, H,
        e0W, e0b, e0s, e0t, e1W, e1b, e1s, e1t,
        c0W, c0b, c0s, c0t, c1W, c1b, c1s, c1t,
        n0W, n0b, n0s, n0t,
        G1, G2, W1f, W2Tf, o1v, o2w3, Wnf, onOff, wd2, misc, knnIdx, o1p);
    egnn_main<<<dim3(Bn * Nn / GI), dim3(TMAIN), 0, stream>>>(X, H,
        G1, G2, W1f, W2Tf, o1p, o2w3, Wnf, onOff, wd2, misc, knnIdx, out);
}

// Round 14
// 154.509 us; speedup vs baseline: 1.1048x; 1.1048x over previous
//
#include <hip/hip_runtime.h>
#include <hip/hip_bf16.h>

#define Bn  2
#define Nn  768
#define Dh  32
#define DMm 64
#define KK  16
#define GI  3                // i's per main block -> grid 512
#define TPRE 256
#define TMAIN 512

typedef __bf16 bf16x8 __attribute__((ext_vector_type(8)));
typedef float  f32x4  __attribute__((ext_vector_type(4)));

// FINAL: round-10 configuration, the verified session optimum.
// Session ledger (main-kernel dur):
//   r4 120us -> r5 101.7 (LDS conflict fix) -> r6 61.5 (6x amortize, knn to pre)
//   -> r10 57.1 (in-register transpose via pi-permuted W2^T; conflicts 591k->4k)
//   Falsified: r7 min-waves=4 (VGPR64 spill, 128us), r8/r9 occupancy raises
//   (neutral/worse), r11 dual-tile ILP (spill, 74us), r12 prefetch@128cap
//   (spill, 65us), r13 prefetch@256thr (200 VGPR -> 2 waves/SIMD, 74us).
//   Operating point: 4 waves/SIMD, VGPR 100, zero spill, 4k LDS conflicts.

// ws layout (bytes):
//   G1     bf16[98304]  @ 0        (196608)
//   G2     f32 [98304]  @ 196608   (393216)
//   W1f    bf16[4096]   @ 589824   (8192)   e1W folded; A-frag of W1^T == B-frag of W1
//   W2Tf   bf16[4096]   @ 598016   (8192)   c0W^T folded, k-permuted by pi
//   o1v    f32[64]      @ 606208
//   o2w3   f32[2048]    @ 606464   (8192)
//   Wnf    f32[3072]    @ 614656   (12288)
//   onOff  f32[32]      @ 626944
//   wd2    f32[64]      @ 627072
//   misc   f32[4]       @ 627328
//   knnIdx int[24576]   @ 627456   (98304)
//   o1p    f32[1024]    @ 725760   (4096)

// ---------------- phase 1: knn (blocks 0..383), G1/G2 (384..431), packing (432)
__global__ __launch_bounds__(TPRE) void egnn_pre(
    const float* __restrict__ X,  const float* __restrict__ H,
    const float* __restrict__ e0W, const float* __restrict__ e0b,
    const float* __restrict__ e0s, const float* __restrict__ e0t,
    const float* __restrict__ e1W, const float* __restrict__ e1b,
    const float* __restrict__ e1s, const float* __restrict__ e1t,
    const float* __restrict__ c0W, const float* __restrict__ c0b,
    const float* __restrict__ c0s, const float* __restrict__ c0t,
    const float* __restrict__ c1W, const float* __restrict__ c1b,
    const float* __restrict__ c1s, const float* __restrict__ c1t,
    const float* __restrict__ n0W, const float* __restrict__ n0b,
    const float* __restrict__ n0s, const float* __restrict__ n0t,
    __bf16* __restrict__ G1, float* __restrict__ G2,
    __bf16* __restrict__ W1f, __bf16* __restrict__ W2Tf,
    float* __restrict__ o1v, float* __restrict__ o2w3,
    float* __restrict__ Wnf, float* __restrict__ onOff,
    float* __restrict__ wd2, float* __restrict__ misc,
    int* __restrict__ knnIdx, float* __restrict__ o1p)
{
    const int tid = threadIdx.x;
    if (blockIdx.x < 384) {
        // ---- knn: one wave per i ----
        const int lane = tid & 63;
        const int row_i = blockIdx.x * 4 + (tid >> 6);   // 0..1535
        const int b = row_i / Nn;
        const float xi0 = X[(size_t)row_i * 3 + 0];
        const float xi1 = X[(size_t)row_i * 3 + 1];
        const float xi2 = X[(size_t)row_i * 3 + 2];
        float v[Nn / 64];
        #pragma unroll
        for (int k = 0; k < Nn / 64; ++k) {
            int j = lane + (k << 6);
            size_t rj = (size_t)(b * Nn + j) * 3;
            float dx = X[rj + 0] - xi0;
            float dy = X[rj + 1] - xi1;
            float dz = X[rj + 2] - xi2;
            v[k] = __fadd_rn(__fadd_rn(__fmul_rn(dx, dx), __fmul_rn(dy, dy)),
                             __fmul_rn(dz, dz));
        }
        for (int r = 0; r < KK; ++r) {
            float bv = 3.4e38f; int bidx = Nn;
            #pragma unroll
            for (int k = 0; k < Nn / 64; ++k)
                if (v[k] < bv) { bv = v[k]; bidx = lane + (k << 6); }
            #pragma unroll
            for (int off = 32; off >= 1; off >>= 1) {
                float ov = __shfl_down(bv, off);
                int   oi = __shfl_down(bidx, off);
                if (ov < bv || (ov == bv && oi < bidx)) { bv = ov; bidx = oi; }
            }
            bidx = __shfl(bidx, 0);
            if (lane == 0) knnIdx[row_i * KK + r] = bidx;
            if ((bidx & 63) == lane) v[bidx >> 6] = 3.4e38f;
        }
    } else if (blockIdx.x < 432) {
        // ---- G1/G2: 48 blocks x 32 rows ----
        __shared__ float sWa[Dh * DMm], sWb[Dh * DMm], sOff[DMm], sH[32 * Dh];
        for (int k = tid; k < Dh * DMm; k += TPRE) {
            float s = e0s[k & 63];
            sWa[k] = e0W[k] * s;
            sWb[k] = e0W[Dh * DMm + k] * s;
        }
        if (tid < DMm) sOff[tid] = fmaf(e0b[tid], e0s[tid], e0t[tid]);
        const int row0 = (blockIdx.x - 384) * 32;
        for (int k = tid; k < 32 * Dh; k += TPRE) sH[k] = H[(size_t)row0 * Dh + k];
        __syncthreads();

        const int r = tid >> 3, g = tid & 7;
        float g1[8], g2[8];
        #pragma unroll
        for (int e = 0; e < 8; ++e) { g1[e] = 0.f; g2[e] = sOff[g * 8 + e]; }
        #pragma unroll
        for (int d = 0; d < Dh; ++d) {
            float hv = sH[r * Dh + d];
            #pragma unroll
            for (int e = 0; e < 8; ++e) {
                g1[e] = fmaf(hv, sWa[d * DMm + g * 8 + e], g1[e]);
                g2[e] = fmaf(hv, sWb[d * DMm + g * 8 + e], g2[e]);
            }
        }
        const size_t row = row0 + r;
        bf16x8 o;
        #pragma unroll
        for (int e = 0; e < 8; ++e) o[e] = (__bf16)g1[e];
        *(bf16x8*)(G1 + row * DMm + g * 8) = o;
        *(float4*)(G2 + row * DMm + g * 8)     = make_float4(g2[0], g2[1], g2[2], g2[3]);
        *(float4*)(G2 + row * DMm + g * 8 + 4) = make_float4(g2[4], g2[5], g2[6], g2[7]);
    } else {
        // ---- weight packing ----
        for (int src = tid; src < 4096; src += TPRE) {
            int k = src >> 6, n = src & 63;
            int fi1 = ((((k >> 5) * 4 + (n >> 4)) * 64) + ((k >> 3) & 3) * 16 + (n & 15)) * 8 + (k & 7);
            W1f[fi1] = (__bf16)(e1W[src] * e1s[n]);
            // W2Tf with pi-permuted k: ch1 = (2s+u)*16 + q*4 + r, ch2 = t4*16 + l15
            int ch1 = k, ch2 = n;
            int s2 = ch1 >> 5, u2 = (ch1 >> 4) & 1, q2 = (ch1 >> 2) & 3, r2 = ch1 & 3;
            int fi2 = (((s2 * 4 + (ch2 >> 4)) * 64) + q2 * 16 + (ch2 & 15)) * 8 + (u2 * 4 + r2);
            W2Tf[fi2] = (__bf16)(c0W[src] * c0s[ch2]);
        }
        if (tid < DMm) {
            o1v[tid] = fmaf(e1b[tid], e1s[tid], e1t[tid]);
            wd2[tid] = e0W[64 * DMm + tid] * e0s[tid];
        }
        for (int u = tid; u < 1024; u += TPRE) {
            int lane = u >> 4, t4 = (u >> 2) & 3, r = u & 3;
            int ch = t4 * 16 + ((lane >> 4) & 3) * 4 + r;
            o1p[u] = fmaf(e1b[ch], e1s[ch], e1t[ch]);
        }
        for (int u = tid; u < 1024; u += TPRE) {
            int lane = u >> 4, rem = u & 15, t4 = rem >> 2, r = rem & 3;
            int ch = t4 * 16 + (lane >> 4) * 4 + r;
            o2w3[2 * u]     = fmaf(c0b[ch], c0s[ch], c0t[ch]);
            o2w3[2 * u + 1] = c1W[ch] * c1s[0];
        }
        for (int idx = tid; idx < (Dh + DMm) * Dh; idx += TPRE)
            Wnf[idx] = n0W[idx] * n0s[idx & 31];
        if (tid < Dh) onOff[tid] = fmaf(n0b[tid], n0s[tid], n0t[tid]);
        if (tid == 0) misc[0] = fmaf(c1b[0], c1s[0], c1t[0]);
    }
}

// ---------------- phase 2: GI=3 i's per block, 8 waves, grid 512 (r10 exact)
__global__ __launch_bounds__(TMAIN, 2) void egnn_main(
    const float* __restrict__ X,  const float* __restrict__ H,
    const __bf16* __restrict__ G1, const float* __restrict__ G2,
    const __bf16* __restrict__ W1f, const __bf16* __restrict__ W2Tf,
    const float* __restrict__ o1p, const float* __restrict__ o2w3,
    const float* __restrict__ Wnf, const float* __restrict__ onOff,
    const float* __restrict__ wd2, const float* __restrict__ misc,
    const int* __restrict__ knnIdx,
    float* __restrict__ out)
{
    const int bid = blockIdx.x;               // 0..511
    const int b  = bid >> 8;
    const int i0 = (bid & 255) * GI;
    const int tid = threadIdx.x;
    const int wv = tid >> 6;                  // 0..7
    const int lane = tid & 63;
    const int l15 = lane & 15;
    const int q   = lane >> 4;

    __shared__ float  sX[Nn * 3];             // 9216
    __shared__ float  sD2[GI * Nn];           // 9216  (sign bit = knn-hit flag)
    __shared__ float  sWj[GI * Nn];           // 9216
    __shared__ float  sMnode[GI * DMm];       // 768
    __shared__ float  sFeat[GI * 96];         // 1152
    __shared__ float  sXacc[GI * 3];
    // total ~29.6 KB

    // ---- phase A1: staging + clears ----
    for (int k = tid; k < Nn * 3; k += TMAIN) sX[k] = X[(size_t)b * Nn * 3 + k];
    if (tid < GI * DMm) sMnode[tid] = 0.f;
    if (tid < GI * Dh) {
        int i_l = tid >> 5, c = tid & 31;
        sFeat[i_l * 96 + c] = H[(size_t)(b * Nn + i0 + i_l) * Dh + c];
    }
    __syncthreads();

    // ---- phase A2: d2 for GI i's ----
    #pragma unroll
    for (int i_l = 0; i_l < GI; ++i_l) {
        float xi0 = sX[(i0 + i_l) * 3 + 0];
        float xi1 = sX[(i0 + i_l) * 3 + 1];
        float xi2 = sX[(i0 + i_l) * 3 + 2];
        for (int j = tid; j < Nn; j += TMAIN) {
            float dx = sX[j * 3 + 0] - xi0;
            float dy = sX[j * 3 + 1] - xi1;
            float dz = sX[j * 3 + 2] - xi2;
            sD2[i_l * Nn + j] = __fadd_rn(__fadd_rn(__fmul_rn(dx, dx), __fmul_rn(dy, dy)),
                                          __fmul_rn(dz, dz));
        }
    }
    __syncthreads();
    // knn hit flags: set sign bit of sD2 at knn indices (distinct -> race-free)
    if (tid < GI * KK) {
        int i_l = tid >> 4, r = tid & 15;
        int idx = knnIdx[(size_t)(b * Nn + i0 + i_l) * KK + r];
        ((unsigned*)sD2)[i_l * Nn + idx] |= 0x80000000u;
    }

    // ---- hoist weight fragments + per-lane constants (registers) ----
    bf16x8 w1f[2][4], w2f[2][4];
    #pragma unroll
    for (int s = 0; s < 2; ++s)
        #pragma unroll
        for (int t4 = 0; t4 < 4; ++t4) {
            w1f[s][t4] = *(const bf16x8*)(W1f + (((s * 4 + t4) * 64 + lane) << 3));
            w2f[s][t4] = *(const bf16x8*)(W2Tf + (((s * 4 + t4) * 64 + lane) << 3));
        }
    bf16x8 wd2b[2];
    #pragma unroll
    for (int s = 0; s < 2; ++s) {
        const float4* wp = (const float4*)(wd2 + s * 32 + q * 8);
        float4 wa = wp[0], wc = wp[1];
        float t[8] = {wa.x, wa.y, wa.z, wa.w, wc.x, wc.y, wc.z, wc.w};
        bf16x8 o;
        #pragma unroll
        for (int e = 0; e < 8; ++e) o[e] = (__bf16)t[e];
        wd2b[s] = o;
    }
    f32x4 o1q[4];
    #pragma unroll
    for (int t4 = 0; t4 < 4; ++t4)
        o1q[t4] = *(const f32x4*)(o1p + lane * 16 + t4 * 4);
    float4 o2w3q[8];
    #pragma unroll
    for (int u = 0; u < 8; ++u) o2w3q[u] = ((const float4*)o2w3)[lane * 8 + u];
    const float c1off = misc[0];
    __syncthreads();

    // ---- main loop: i_l outer, 6 tiles per wave inner ----
    for (int i_l = 0; i_l < GI; ++i_l) {
        const int ig = i0 + i_l;
        bf16x8 g2b[2];
        #pragma unroll
        for (int s = 0; s < 2; ++s) {
            const float4* gp = (const float4*)(G2 + (size_t)(b * Nn + ig) * DMm + s * 32 + q * 8);
            float4 ga = gp[0], gc = gp[1];
            float t[8] = {ga.x, ga.y, ga.z, ga.w, gc.x, gc.y, gc.z, gc.w};
            bf16x8 o;
            #pragma unroll
            for (int e = 0; e < 8; ++e) o[e] = (__bf16)t[e];
            g2b[s] = o;
        }
        for (int t = wv; t < 48; t += 8) {
            const int base = t * 16;
            const int jm = base + l15;

            unsigned du = __float_as_uint(sD2[i_l * Nn + jm]);
            float d2v = __uint_as_float(du & 0x7fffffffu);
            bool hit = (du >> 31) != 0;

            // a0 fragments (used as B operand: B[k=ch0][n=j=l15])
            bf16x8 a0f[2];
            #pragma unroll
            for (int s = 0; s < 2; ++s) {
                bf16x8 g1v = *(const bf16x8*)(G1 + (size_t)(b * Nn + jm) * DMm + s * 32 + q * 8);
                bf16x8 af;
                #pragma unroll
                for (int e = 0; e < 8; ++e) {
                    float v = fmaf(d2v, (float)wd2b[s][e], (float)g2b[s][e]) + (float)g1v[e];
                    af[e] = (__bf16)fmaxf(v, 0.f);
                }
                a0f[s] = af;
            }

            // e1 transposed: acc1 = W1^T x a0^T + o1 -> lane holds a1[j=l15][ch=t4*16+q*4+r]
            f32x4 acc1[4];
            #pragma unroll
            for (int t4 = 0; t4 < 4; ++t4) acc1[t4] = o1q[t4];
            #pragma unroll
            for (int s = 0; s < 2; ++s)
                #pragma unroll
                for (int t4 = 0; t4 < 4; ++t4)
                    acc1[t4] = __builtin_amdgcn_mfma_f32_16x16x32_bf16(w1f[s][t4], a0f[s], acc1[t4], 0, 0, 0);
            #pragma unroll
            for (int t4 = 0; t4 < 4; ++t4)
                #pragma unroll
                for (int r = 0; r < 4; ++r)
                    acc1[t4][r] = fmaxf(acc1[t4][r], 0.f);

            // m_node: this lane holds j=l15's a1 values for 16 distinct channels
            if (hit) {
                #pragma unroll
                for (int t4 = 0; t4 < 4; ++t4)
                    #pragma unroll
                    for (int r = 0; r < 4; ++r)
                        atomicAdd(&sMnode[i_l * DMm + t4 * 16 + q * 4 + r], acc1[t4][r]);
            }

            // in-register transpose via pi: B-frag slot (s, 4u+r) = acc1[2s+u][r]
            bf16x8 bfr[2];
            #pragma unroll
            for (int s = 0; s < 2; ++s) {
                bf16x8 o;
                #pragma unroll
                for (int u = 0; u < 2; ++u)
                    #pragma unroll
                    for (int r = 0; r < 4; ++r)
                        o[u * 4 + r] = (__bf16)acc1[2 * s + u][r];
                bfr[s] = o;
            }

            // c0 (pi-permuted k) + fused c1 dot
            f32x4 acc2[4];
            #pragma unroll
            for (int t4 = 0; t4 < 4; ++t4) acc2[t4] = f32x4{0.f, 0.f, 0.f, 0.f};
            #pragma unroll
            for (int s = 0; s < 2; ++s)
                #pragma unroll
                for (int t4 = 0; t4 < 4; ++t4)
                    acc2[t4] = __builtin_amdgcn_mfma_f32_16x16x32_bf16(w2f[s][t4], bfr[s], acc2[t4], 0, 0, 0);
            float p = 0.f;
            #pragma unroll
            for (int t4 = 0; t4 < 4; ++t4)
                #pragma unroll
                for (int r = 0; r < 4; ++r) {
                    int u = t4 * 4 + r;
                    float4 qv = o2w3q[u >> 1];
                    float o2 = (u & 1) ? qv.z : qv.x;
                    float w3 = (u & 1) ? qv.w : qv.y;
                    p = fmaf(fmaxf(acc2[t4][r] + o2, 0.f), w3, p);
                }
            p += __shfl_xor(p, 16);
            p += __shfl_xor(p, 32);
            if (lane < 16) sWj[i_l * Nn + base + l15] = fmaxf(p + c1off, 0.f);
        }
    }
    __syncthreads();

    // ---- epilogue 1: xacc (waves 0..GI-1, one i each) + m_node -> sFeat ----
    if (wv < GI) {
        const int i_l = wv;
        float xi0 = sX[(i0 + i_l) * 3 + 0];
        float xi1 = sX[(i0 + i_l) * 3 + 1];
        float xi2 = sX[(i0 + i_l) * 3 + 2];
        float xa0 = 0.f, xa1 = 0.f, xa2 = 0.f;
        #pragma unroll
        for (int k = 0; k < Nn / 64; ++k) {
            int j = lane + (k << 6);
            float w = sWj[i_l * Nn + j];
            xa0 = fmaf(w, sX[j * 3 + 0] - xi0, xa0);
            xa1 = fmaf(w, sX[j * 3 + 1] - xi1, xa1);
            xa2 = fmaf(w, sX[j * 3 + 2] - xi2, xa2);
        }
        #pragma unroll
        for (int off = 32; off >= 1; off >>= 1) {
            xa0 += __shfl_down(xa0, off);
            xa1 += __shfl_down(xa1, off);
            xa2 += __shfl_down(xa2, off);
        }
        if (lane == 0) {
            sXacc[i_l * 3 + 0] = xa0;
            sXacc[i_l * 3 + 1] = xa1;
            sXacc[i_l * 3 + 2] = xa2;
        }
    }
    if (tid < GI * DMm) {
        int i_l = tid >> 6, ch = tid & 63;
        sFeat[i_l * 96 + Dh + ch] = sMnode[tid];
    }
    __syncthreads();

    // ---- epilogue 2: n0 layer (Wnf from global, L2-hot) + stores ----
    if (tid < GI * Dh) {
        int i_l = tid >> 5, oc = tid & 31;
        float z = onOff[oc];
        #pragma unroll
        for (int c = 0; c < Dh + DMm; ++c)
            z = fmaf(sFeat[i_l * 96 + c], Wnf[c * Dh + oc], z);
        out[(size_t)Bn * Nn * 3 + (size_t)(b * Nn + i0 + i_l) * Dh + oc] = fmaxf(z, 0.f);
    }
    if (tid < GI * 3) {
        int i_l = tid / 3, c = tid - i_l * 3;
        out[(size_t)(b * Nn + i0 + i_l) * 3 + c] = sX[(i0 + i_l) * 3 + c] + sXacc[i_l * 3 + c];
    }
}

extern "C" void kernel_launch(void* const* d_in, const int* in_sizes, int n_in,
                              void* d_out, int out_size, void* d_ws, size_t ws_size,
                              hipStream_t stream) {
    const float* X   = (const float*)d_in[0];
    const float* H   = (const float*)d_in[1];
    const float* e0W = (const float*)d_in[2];
    const float* e0b = (const float*)d_in[3];
    const float* e0s = (const float*)d_in[4];
    const float* e0t = (const float*)d_in[5];
    const float* e1W = (const float*)d_in[6];
    const float* e1b = (const float*)d_in[7];
    const float* e1s = (const float*)d_in[8];
    const float* e1t = (const float*)d_in[9];
    const float* c0W = (const float*)d_in[10];
    const float* c0b = (const float*)d_in[11];
    const float* c0s = (const float*)d_in[12];
    const float* c0t = (const float*)d_in[13];
    const float* c1W = (const float*)d_in[14];
    const float* c1b = (const float*)d_in[15];
    const float* c1s = (const float*)d_in[16];
    const float* c1t = (const float*)d_in[17];
    const float* n0W = (const float*)d_in[18];
    const float* n0b = (const float*)d_in[19];
    const float* n0s = (const float*)d_in[20];
    const float* n0t = (const float*)d_in[21];
    float* out = (float*)d_out;

    char* ws = (char*)d_ws;
    __bf16* G1    = (__bf16*)(ws);
    float*  G2    = (float*)(ws + 196608);
    __bf16* W1f   = (__bf16*)(ws + 589824);
    __bf16* W2Tf  = (__bf16*)(ws + 598016);
    float*  o1v   = (float*)(ws + 606208);
    float*  o2w3  = (float*)(ws + 606464);
    float*  Wnf   = (float*)(ws + 614656);
    float*  onOff = (float*)(ws + 626944);
    float*  wd2   = (float*)(ws + 627072);
    float*  misc  = (float*)(ws + 627328);
    int*    knnIdx= (int*)(ws + 627456);
    float*  o1p   = (float*)(ws + 725760);

    egnn_pre<<<dim3(433), dim3(TPRE), 0, stream>>>(X, H,
        e0W, e0b, e0s, e0t, e1W, e1b, e1s, e1t,
        c0W, c0b, c0s, c0t, c1W, c1b, c1s, c1t,
        n0W, n0b, n0s, n0t,
        G1, G2, W1f, W2Tf, o1v, o2w3, Wnf, onOff, wd2, misc, knnIdx, o1p);
    egnn_main<<<dim3(Bn * Nn / GI), dim3(TMAIN), 0, stream>>>(X, H,
        G1, G2, W1f, W2Tf, o1p, o2w3, Wnf, onOff, wd2, misc, knnIdx, out);
}